// Round 3
// baseline (91.282 us; speedup 1.0000x reference)
//
#include <hip/hip_runtime.h>

#define B_   4
#define Hf   128
#define Wf   128
#define C_   128
#define HC   32
#define WC   32
#define SR   15
#define PAD  7
#define FR   125      // 125x125 pooled (unpadded) grid

// ---- kernel 1: f_c = avg_pool(features_0, 4, stride 4) -> (4,32,32,128) ----
__global__ __launch_bounds__(256) void pool_fc(const float* __restrict__ in0,
                                               float* __restrict__ fc) {
    int t = blockIdx.x * 256 + threadIdx.x;          // B*32*32*32 float4 = 131072
    int c4 = t & 31;
    int j  = (t >> 5) & 31;
    int i  = (t >> 10) & 31;
    int b  = t >> 15;
    const float4* in = reinterpret_cast<const float4*>(in0);
    int base = ((b * Hf + 4 * i) * Wf + 4 * j) * 32 + c4;   // float4 units
    float4 acc = make_float4(0.f, 0.f, 0.f, 0.f);
#pragma unroll
    for (int dy = 0; dy < 4; ++dy)
#pragma unroll
        for (int dx = 0; dx < 4; ++dx) {
            float4 v = in[base + dy * (Wf * 32) + dx * 32];
            acc.x += v.x; acc.y += v.y; acc.z += v.z; acc.w += v.w;
        }
    const float s = 1.0f / 16.0f;
    acc.x *= s; acc.y *= s; acc.z *= s; acc.w *= s;
    reinterpret_cast<float4*>(fc)[t] = acc;
}

// ---- kernel 2: f_r = avg_pool(features_0from1, 4, stride 1) -> (4,125,125,128), NO pad ----
__device__ inline float4 hsum4(const float4* __restrict__ base, int row, int xcol) {
    float4 s = make_float4(0.f, 0.f, 0.f, 0.f);
#pragma unroll
    for (int dx = 0; dx < 4; ++dx) {
        float4 v = base[(row * Wf + xcol + dx) * 32];
        s.x += v.x; s.y += v.y; s.z += v.z; s.w += v.w;
    }
    return s;
}

__global__ __launch_bounds__(256) void pool_fr(const float* __restrict__ in1,
                                               float* __restrict__ fr) {
    int blk   = blockIdx.x;
    int strip = blk & 15;
    int xt    = (blk >> 4) & 15;
    int b     = blk >> 8;
    int c4    = threadIdx.x & 31;
    int x     = xt * 8 + (threadIdx.x >> 5);
    if (x >= FR) return;
    int y0 = strip * 8;

    const float4* base = reinterpret_cast<const float4*>(in1) + (b * Hf * Wf) * 32 + c4;
    float4* fr4 = reinterpret_cast<float4*>(fr);

    float4 h[11];
#pragma unroll
    for (int k = 0; k < 11; ++k) {
        int r = y0 + k; if (r > Hf - 1) r = Hf - 1;
        h[k] = hsum4(base, r, x);
    }
    const float s = 1.0f / 16.0f;
#pragma unroll
    for (int yy = 0; yy < 8; ++yy) {
        int y = y0 + yy;
        if (y < FR) {
            float4 o;
            o.x = (h[yy].x + h[yy+1].x + h[yy+2].x + h[yy+3].x) * s;
            o.y = (h[yy].y + h[yy+1].y + h[yy+2].y + h[yy+3].y) * s;
            o.z = (h[yy].z + h[yy+1].z + h[yy+2].z + h[yy+3].z) * s;
            o.w = (h[yy].w + h[yy+1].w + h[yy+2].w + h[yy+3].w) * s;
            fr4[((b * FR + y) * FR + x) * 32 + c4] = o;
        }
    }
}

// ---- kernel 3: correlation + leaky_relu + 4x4 replicate ----
// block per coarse cell; 64 groups x 4 lanes; lane-in-group owns 32 channels
__global__ __launch_bounds__(256) void corr_kernel(const float* __restrict__ fc,
                                                   const float* __restrict__ fr,
                                                   float* __restrict__ out) {
    int blk  = blockIdx.x;
    int cell = (blk & 7) * 512 + (blk >> 3);         // XCD-aware swizzle (4096 % 8 == 0)
    int j = cell & 31;
    int i = (cell >> 5) & 31;
    int b = cell >> 10;

    int tid = threadIdx.x;
    int sl  = tid & 3;                               // lane in 4-lane group
    int grp = tid >> 2;                              // 0..63

    __shared__ float corr_rep[900];                  // 4x replicated corr (dj-major)

    const float4* fc4 = reinterpret_cast<const float4*>(fc);
    const float4* fr4 = reinterpret_cast<const float4*>(fr);

    // my 32-channel slice of f_c (8 float4 = 32 VGPRs)
    float4 f[8];
    int fcbase = ((b * HC + i) * WC + j) * 32 + sl * 8;
#pragma unroll
    for (int k = 0; k < 8; ++k) f[k] = fc4[fcbase + k];

#pragma unroll
    for (int it = 0; it < 4; ++it) {
        int uv = it * 64 + grp;                      // 0..255, mask >=225
        int u = uv / SR, v = uv - u * SR;
        int row = 4 * i + u - PAD;
        int col = 4 * j + v - PAD;
        bool ok = (uv < SR * SR) && row >= 0 && row < FR && col >= 0 && col < FR;

        float a0 = 0.f, a1 = 0.f;
        if (ok) {
            const float4* p = fr4 + ((b * FR + row) * FR + col) * 32 + sl * 8;
#pragma unroll
            for (int k = 0; k < 8; k += 2) {
                float4 r0 = p[k], r1 = p[k + 1];
                float4 q0 = f[k], q1 = f[k + 1];
                a0 = fmaf(q0.x, r0.x, a0); a0 = fmaf(q0.y, r0.y, a0);
                a0 = fmaf(q0.z, r0.z, a0); a0 = fmaf(q0.w, r0.w, a0);
                a1 = fmaf(q1.x, r1.x, a1); a1 = fmaf(q1.y, r1.y, a1);
                a1 = fmaf(q1.z, r1.z, a1); a1 = fmaf(q1.w, r1.w, a1);
            }
        }
        float acc = a0 + a1;
        acc += __shfl_xor(acc, 1);
        acc += __shfl_xor(acc, 2);                   // all 4 lanes now hold the dot
        if (uv < SR * SR) {
            float c = acc * (1.0f / 128.0f);
            float val = c > 0.f ? c : 0.1f * c;
            corr_rep[sl * SR * SR + uv] = val;       // builds 900-float replicated array
        }
    }
    __syncthreads();

    // 16 pixels x 225 floats = 4 rows x 900 consecutive floats; float4 stores
    float4* out4 = reinterpret_cast<float4*>(out);
    long pix  = (long)(b * Hf + 4 * i) * Wf + 4 * j; // divisible by 4
    long base4 = pix * (SR * SR) / 4;
    if (tid < SR * SR) {
        float4 val = *reinterpret_cast<const float4*>(&corr_rep[4 * tid]);
#pragma unroll
        for (int di = 0; di < 4; ++di)
            out4[base4 + di * (Wf * SR * SR / 4) + tid] = val;
    }
}

extern "C" void kernel_launch(void* const* d_in, const int* in_sizes, int n_in,
                              void* d_out, int out_size, void* d_ws, size_t ws_size,
                              hipStream_t stream) {
    const float* f0 = (const float*)d_in[0];
    const float* f1 = (const float*)d_in[1];
    float* out = (float*)d_out;

    float* fc = (float*)d_ws;                        // 2 MB
    float* fr = fc + B_ * HC * WC * C_;              // 32 MB

    pool_fc<<<(B_ * HC * WC * 32) / 256, 256, 0, stream>>>(f0, fc);
    pool_fr<<<B_ * 16 * 16, 256, 0, stream>>>(f1, fr);
    corr_kernel<<<B_ * HC * WC, 256, 0, stream>>>(fc, fr, out);
}

// Round 4
// 44.382 us; speedup vs baseline: 2.0567x; 2.0567x over previous
//
#include <hip/hip_runtime.h>
#include <hip/hip_bf16.h>

#define B_   4
#define Hf   128
#define Wf   128
#define HC   32
#define WC   32
#define SR   15
#define PAD  7
#define FR   125

static __device__ __forceinline__ unsigned short f2bf(float x) {
    __hip_bfloat16 h = __float2bfloat16(x);
    unsigned short u; __builtin_memcpy(&u, &h, 2); return u;
}

// segmented pair-merge: bit=0 lanes keep x-partials, bit=1 lanes keep y-partials
static __device__ __forceinline__ float mrg(float x, float y, bool hi, int m) {
    float u0 = hi ? x : y;
    float t  = __shfl_xor(u0, m, 64);
    return (hi ? y : x) + t;
}

// ---- fused pooling: blocks [0,1024) -> f_r (bf16), [1024,1536) -> f_c (fp32) ----
__global__ __launch_bounds__(256) void pool_fused(const float* __restrict__ in0,
                                                  const float* __restrict__ in1,
                                                  float* __restrict__ fc,
                                                  unsigned short* __restrict__ fr16) {
    int bid = blockIdx.x;
    if (bid < 1024) {
        // f_r = avg_pool(in1, 4, stride 1) -> (4,125,125,128) bf16, no pad
        int strip = bid & 15;
        int xt    = (bid >> 4) & 15;
        int b     = bid >> 8;
        int c4    = threadIdx.x & 31;
        int x     = xt * 8 + (threadIdx.x >> 5);
        if (x >= FR) return;
        int y0 = strip * 8;

        const float4* base = reinterpret_cast<const float4*>(in1) + (b * Hf * Wf) * 32 + c4;
        float4 h[11];
#pragma unroll
        for (int k = 0; k < 11; ++k) {
            int r = y0 + k; if (r > Hf - 1) r = Hf - 1;
            float4 s = make_float4(0.f, 0.f, 0.f, 0.f);
#pragma unroll
            for (int dx = 0; dx < 4; ++dx) {
                float4 v = base[(r * Wf + x + dx) * 32];
                s.x += v.x; s.y += v.y; s.z += v.z; s.w += v.w;
            }
            h[k] = s;
        }
        const float s = 1.0f / 16.0f;
        ushort4* fr4 = reinterpret_cast<ushort4*>(fr16);
#pragma unroll
        for (int yy = 0; yy < 8; ++yy) {
            int y = y0 + yy;
            if (y < FR) {
                ushort4 o;
                o.x = f2bf((h[yy].x + h[yy+1].x + h[yy+2].x + h[yy+3].x) * s);
                o.y = f2bf((h[yy].y + h[yy+1].y + h[yy+2].y + h[yy+3].y) * s);
                o.z = f2bf((h[yy].z + h[yy+1].z + h[yy+2].z + h[yy+3].z) * s);
                o.w = f2bf((h[yy].w + h[yy+1].w + h[yy+2].w + h[yy+3].w) * s);
                fr4[((b * FR + y) * FR + x) * 32 + c4] = o;
            }
        }
    } else {
        // f_c = avg_pool(in0, 4, stride 4) -> (4,32,32,128) fp32
        int t = (bid - 1024) * 256 + threadIdx.x;
        int c4 = t & 31;
        int j  = (t >> 5) & 31;
        int i  = (t >> 10) & 31;
        int b  = t >> 15;
        const float4* in = reinterpret_cast<const float4*>(in0);
        int base = ((b * Hf + 4 * i) * Wf + 4 * j) * 32 + c4;
        float4 acc = make_float4(0.f, 0.f, 0.f, 0.f);
#pragma unroll
        for (int dy = 0; dy < 4; ++dy)
#pragma unroll
            for (int dx = 0; dx < 4; ++dx) {
                float4 v = in[base + dy * (Wf * 32) + dx * 32];
                acc.x += v.x; acc.y += v.y; acc.z += v.z; acc.w += v.w;
            }
        const float sc = 1.0f / 16.0f;
        acc.x *= sc; acc.y *= sc; acc.z *= sc; acc.w *= sc;
        reinterpret_cast<float4*>(fc)[t] = acc;
    }
}

// ---- correlation + leaky_relu + 4x4 replicate ----
// block per cell; 8 groups x 32 lanes; group g owns u = g, g+8; lane = 4 channels
__global__ __launch_bounds__(256) void corr_kernel(const float* __restrict__ fc,
                                                   const unsigned short* __restrict__ fr16,
                                                   float* __restrict__ out) {
    int blk  = blockIdx.x;
    int cell = (blk & 7) * 512 + (blk >> 3);         // XCD swizzle (4096 % 8 == 0)
    int j = cell & 31;
    int i = (cell >> 5) & 31;
    int b = cell >> 10;

    int tid = threadIdx.x;
    int g   = tid >> 5;                              // group 0..7
    int gl  = tid & 31;                              // lane in group = channel chunk

    __shared__ float corr_rep[900];

    float4 f = reinterpret_cast<const float4*>(fc)[((b * HC + i) * WC + j) * 32 + gl];

    int colbase = 4 * j - PAD;
    int vmin = max(0, -colbase);
    int vmax = min(SR - 1, FR - 1 - colbase);

    const uint2* frbase = reinterpret_cast<const uint2*>(fr16);
    bool h16 = gl & 16, h8 = gl & 8, h4 = gl & 4, h2 = gl & 2;
    int vidx = ((gl >> 4) & 1) * 8 + ((gl >> 3) & 1) * 4 + ((gl >> 2) & 1) * 2 + ((gl >> 1) & 1);

#pragma unroll
    for (int pass = 0; pass < 2; ++pass) {
        int u = g + pass * 8;
        if (u < SR) {
            int row = 4 * i + u - PAD;
            bool rowok = (row >= 0) && (row < FR);

            float a[16];
#pragma unroll
            for (int k = 0; k < 16; ++k) a[k] = 0.f;

            if (rowok) {
                const uint2* p = frbase + ((b * FR + row) * FR + colbase) * 32 + gl;
#pragma unroll
                for (int v = 0; v < SR; ++v) {
                    if (v >= vmin && v <= vmax) {      // block-uniform scalar branch
                        uint2 w = p[v * 32];
                        float r0 = __uint_as_float(w.x << 16);
                        float r1 = __uint_as_float(w.x & 0xffff0000u);
                        float r2 = __uint_as_float(w.y << 16);
                        float r3 = __uint_as_float(w.y & 0xffff0000u);
                        a[v] = fmaf(f.x, r0, fmaf(f.y, r1, fmaf(f.z, r2, f.w * r3)));
                    }
                }
            }

            // merge-tree reduce: 16 accs over 32 lanes -> each lane holds sum of a[vidx]
            float bb[8], cc[4], dd[2], e;
#pragma unroll
            for (int k = 0; k < 8; ++k) bb[k] = mrg(a[k], a[k + 8], h16, 16);
#pragma unroll
            for (int k = 0; k < 4; ++k) cc[k] = mrg(bb[k], bb[k + 4], h8, 8);
#pragma unroll
            for (int k = 0; k < 2; ++k) dd[k] = mrg(cc[k], cc[k + 2], h4, 4);
            e = mrg(dd[0], dd[1], h2, 2);
            e += __shfl_xor(e, 1, 64);

            if (vidx < SR) {
                float cv = e * (1.0f / 128.0f);
                float val = cv > 0.f ? cv : 0.1f * cv;
                int uvq = u * SR + vidx;
                int c0 = (gl & 1) * 225;
                corr_rep[c0 + uvq] = val;
                corr_rep[c0 + 450 + uvq] = val;
            }
        }
    }
    __syncthreads();

    // 16 pixels x 225 floats = 4 rows x 900 consecutive floats; float4 stores
    if (tid < SR * SR) {
        float4 val = *reinterpret_cast<const float4*>(&corr_rep[4 * tid]);
        float4* out4 = reinterpret_cast<float4*>(out);
        long pix  = (long)(b * Hf + 4 * i) * Wf + 4 * j;   // divisible by 4
        long base4 = pix * (SR * SR) / 4;
#pragma unroll
        for (int di = 0; di < 4; ++di)
            out4[base4 + di * (Wf * SR * SR / 4) + tid] = val;
    }
}

extern "C" void kernel_launch(void* const* d_in, const int* in_sizes, int n_in,
                              void* d_out, int out_size, void* d_ws, size_t ws_size,
                              hipStream_t stream) {
    const float* f0 = (const float*)d_in[0];
    const float* f1 = (const float*)d_in[1];
    float* out = (float*)d_out;

    float* fc = (float*)d_ws;                                  // 2 MB fp32
    unsigned short* fr16 = (unsigned short*)(fc + B_ * HC * WC * 128);  // 16 MB bf16

    pool_fused<<<1536, 256, 0, stream>>>(f0, f1, fc, fr16);
    corr_kernel<<<B_ * HC * WC, 256, 0, stream>>>(fc, fr16, out);
}